// Round 1
// 1116.655 us; speedup vs baseline: 1.0081x; 1.0081x over previous
//
#include <hip/hip_runtime.h>

typedef _Float16 half8 __attribute__((ext_vector_type(8)));
typedef float floatx4 __attribute__((ext_vector_type(4)));

#define B_TOT 65536
#define K_TOT 1024
#define D_TOT 256

// d_out offsets (float elements), concatenated reference outputs:
// quantized(B*D), vq_loss(1), entropy(1), hard_inds(B), hard_q(B*D), enc_inds(B*K), cluster(1)
#define OFF_Q    0
#define OFF_LOSS 16777216
#define OFF_ENT  16777217
#define OFF_IDX  16777218
#define OFF_HQ   16842754
#define OFF_P    33619970
#define OFF_CM   100728834

// ws offsets (bytes)
#define WS_E16   0          // K*D fp16        (512 KB)
#define WS_ETB   524288     // E^T tiled fp16: [kt][d][kl] 32x256x32 (512 KB)
#define WS_E2    1048576    // K floats
#define WS_INV   1052672    // (unused now)
#define WS_MIND  1314816    // B floats (row min dist)
#define WS_FLAG  1576960    // B ints (flagged row list)
#define WS_CNT   1839104    // int counter
#define WS_LSUM  1839108    // float loss sum
#define WS_CSUM  1839112    // float cluster sum
#define WS_COL   1839120    // 1024 floats col sums

#define THETA 1e-4f

// async global->LDS, 16B per lane, linear LDS dest (wave-uniform base + lane*16)
__device__ __forceinline__ void gll16(const void* g, void* l) {
  __builtin_amdgcn_global_load_lds(
      (const __attribute__((address_space(1))) void*)g,
      (__attribute__((address_space(3))) void*)l, 16, 0, 0);
}

#define ASM_WAIT_LGKM()     asm volatile("s_waitcnt lgkmcnt(0)" ::: "memory")
#define ASM_WAIT_VM0_LGKM() asm volatile("s_waitcnt vmcnt(0) lgkmcnt(0)" ::: "memory")
#define ASM_WAIT_VM8_LGKM() asm volatile("s_waitcnt vmcnt(8) lgkmcnt(0)" ::: "memory")
#define HARD_BARRIER() do { __builtin_amdgcn_s_barrier(); \
  asm volatile("" ::: "memory"); __builtin_amdgcn_sched_barrier(0); } while (0)

// exact replica of numpy pairwise_sum for n=128 (<= blocksize): 8 accumulators
__device__ __forceinline__ float np_pw128(const float* a) {
  float r0=a[0],r1=a[1],r2=a[2],r3=a[3],r4=a[4],r5=a[5],r6=a[6],r7=a[7];
  for (int i = 8; i < 128; i += 8) {
    r0+=a[i+0]; r1+=a[i+1]; r2+=a[i+2]; r3+=a[i+3];
    r4+=a[i+4]; r5+=a[i+5]; r6+=a[i+6]; r7+=a[i+7];
  }
  return ((r0+r1)+(r2+r3))+((r4+r5)+(r6+r7));
}

__global__ void vq_prep(const float* __restrict__ emb, char* ws) {
  _Float16* E16 = (_Float16*)(ws + WS_E16);
  _Float16* ETb = (_Float16*)(ws + WS_ETB);
  float* e2g = (float*)(ws + WS_E2);
  int k = blockIdx.x, d = threadIdx.x;
  float v = emb[k*256 + d];
  E16[k*256 + d] = (_Float16)v;
  ETb[(k>>5)*8192 + d*32 + (k&31)] = (_Float16)v;
  __shared__ float sq[256];
  sq[d] = v*v;
  __syncthreads();
  if (d == 0) e2g[k] = np_pw128(sq) + np_pw128(sq+128);
  if (blockIdx.x == 0) {
    float* col = (float*)(ws + WS_COL);
    col[d] = 0.f; col[256+d] = 0.f; col[512+d] = 0.f; col[768+d] = 0.f;
    if (d == 0) {
      *(int*)(ws + WS_CNT) = 0;
      *(float*)(ws + WS_LSUM) = 0.f;
      *(float*)(ws + WS_CSUM) = 0.f;
    }
  }
}

// main fused kernel, two passes over K tiles:
//  pass1: GEMM1 only -> row min / second-min / sum(exp)  (no global stores)
//  pass2: GEMM1 recompute -> write NORMALIZED P (nontemporal) + fp16 A-buf,
//         entropy column partials (LDS), GEMM2 -> Q, loss; HQ gather fused.
// Barriers are lgkm-only / counted-vmcnt; P stores are never drained in-loop.
__global__ __launch_bounds__(256, 2) void vq_main(const float* __restrict__ latents,
                                                  const float* __restrict__ emb,
                                                  char* ws, float* __restrict__ dout) {
  const _Float16* E16 = (const _Float16*)(ws + WS_E16);
  const _Float16* ETb = (const _Float16*)(ws + WS_ETB);
  const float* e2g = (const float*)(ws + WS_E2);
  float* mindg = (float*)(ws + WS_MIND);
  int* flag = (int*)(ws + WS_FLAG);
  int* cnt = (int*)(ws + WS_CNT);
  float* lsum = (float*)(ws + WS_LSUM);
  float* csum = (float*)(ws + WS_CSUM);
  float* colg = (float*)(ws + WS_COL);

  // LDS: 32K dbuf E + 16K ET + 4K A + 4K e2 + 4K colsum + misc = ~60.5 KB
  __shared__ _Float16 bufE[2][32*256];  // [r][d], chunk' = chunk ^ r
  __shared__ _Float16 bufET[256*32];    // [d][kl], chunk' = chunk ^ ((d>>1)&3)
  __shared__ _Float16 ldsA[64*32];      // [row][kl], chunk' = chunk ^ ((row>>1)&3)
  __shared__ float lds_e2[1024];
  __shared__ float lds_cs[1024];
  __shared__ float lds_inv[64];
  __shared__ int   lds_idx[64];
  __shared__ float lds_red[4];

  int tid = threadIdx.x;
  int wave = tid >> 6, lane = tid & 63;
  int l15 = lane & 15, quad = lane >> 4;
  int blk = blockIdx.x;

  // ---- A fragments (latents rows, fp16) in registers + c = sum(l^2) ----
  half8 afrag[8];
  float c = 0.f;
  {
    int rowg = blk*64 + wave*16 + l15;
    const float* lr = latents + (size_t)rowg*256;
#pragma unroll
    for (int ks = 0; ks < 8; ks++) {
      const float4* p = (const float4*)(lr + ks*32 + quad*8);
      float4 x = p[0], y = p[1];
      half8 h;
      h[0]=(_Float16)x.x; h[1]=(_Float16)x.y; h[2]=(_Float16)x.z; h[3]=(_Float16)x.w;
      h[4]=(_Float16)y.x; h[5]=(_Float16)y.y; h[6]=(_Float16)y.z; h[7]=(_Float16)y.w;
      afrag[ks] = h;
      c += x.x*x.x + x.y*x.y + x.z*x.z + x.w*x.w
         + y.x*y.x + y.y*y.y + y.z*y.z + y.w*y.w;
    }
    c += __shfl_xor(c, 16);
    c += __shfl_xor(c, 32);
  }

  // staging helpers: linear LDS dest, pre-swizzled global source (matches LDS
  // slot(r,cs) <- global chunk (cs ^ swz) convention used by the ds_reads).
  auto STAGE_E = [&](int kt, int nb) {
    int k0 = kt*32;
#pragma unroll
    for (int j = 0; j < 4; j++) {
      int r = wave*8 + j*2 + (lane>>5);
      int cch = lane & 31;
      gll16(E16 + (size_t)(k0 + r)*256 + ((cch ^ r)&31)*8,
            &bufE[nb][(wave*8 + j*2)*256]);
    }
  };
  auto STAGE_ET = [&](int kt) {
#pragma unroll
    for (int j = 0; j < 4; j++) {
      int d = wave*64 + j*16 + (lane>>2);
      int cch = lane & 3;
      gll16(ETb + (size_t)kt*8192 + d*32 + ((cch ^ ((d>>1)&3))*8),
            &bufET[(wave*64 + j*16)*32]);
    }
  };

  // ---- prologue: e2 + colsum init, prefetch tile 0 ----
#pragma unroll
  for (int j = 0; j < 4; j++) {
    lds_e2[tid + 256*j] = e2g[tid + 256*j];
    lds_cs[tid + 256*j] = 0.f;
  }
  STAGE_E(0, 0);
  ASM_WAIT_VM0_LGKM();
  HARD_BARRIER();

  float m1[4], m2[4], ssum[4]; int i1[4];
#pragma unroll
  for (int r = 0; r < 4; r++) { m1[r]=1e30f; m2[r]=1e30f; ssum[r]=0.f; i1[r]=0; }
  floatx4 zz = {0.f,0.f,0.f,0.f};

  // ================= PASS 1: sums/min only =================
  for (int kt = 0; kt < 32; kt++) {
    int cur = kt & 1;
    STAGE_E((kt+1)&31, cur^1);     // kt=31 prefetches tile 0 for pass 2
    __builtin_amdgcn_sched_barrier(0);
    int k0 = kt*32;
    const _Float16* Ecur = &bufE[cur][0];

    floatx4 sacc[2]; sacc[0] = zz; sacc[1] = zz;
#pragma unroll
    for (int ks = 0; ks < 8; ks++) {
#pragma unroll
      for (int nt = 0; nt < 2; nt++) {
        int r = nt*16 + l15;
        half8 b = *(const half8*)(&Ecur[r*256 + (((ks*4+quad) ^ r)&31)*8]);
        sacc[nt] = __builtin_amdgcn_mfma_f32_16x16x32_f16(afrag[ks], b, sacc[nt], 0, 0, 0);
      }
    }
#pragma unroll
    for (int nt = 0; nt < 2; nt++) {
      int kl = nt*16 + l15;
      int kcol = k0 + kl;
      float e2v = lds_e2[kcol];
#pragma unroll
      for (int reg = 0; reg < 4; reg++) {
        float v = fmaf(-2.f, sacc[nt][reg], e2v);
        if (v < m1[reg]) { m2[reg] = m1[reg]; m1[reg] = v; i1[reg] = kcol; }
        else if (v < m2[reg]) m2[reg] = v;
        ssum[reg] += __expf(-10.f * v);
      }
    }
    ASM_WAIT_VM0_LGKM();   // next tile's glls done; all ds_reads done
    HARD_BARRIER();
  }

  // ---- row reductions across the 16 l15 lanes ----
#pragma unroll
  for (int reg = 0; reg < 4; reg++) {
#pragma unroll
    for (int mbit = 1; mbit < 16; mbit <<= 1) {
      float om1 = __shfl_xor(m1[reg], mbit);
      int   oi1 = __shfl_xor(i1[reg], mbit);
      float om2 = __shfl_xor(m2[reg], mbit);
      float os  = __shfl_xor(ssum[reg], mbit);
      ssum[reg] += os;
      bool take = (om1 < m1[reg]) || (om1 == m1[reg] && oi1 < i1[reg]);
      float big = take ? m1[reg] : om1;
      if (take) { m1[reg] = om1; i1[reg] = oi1; }
      m2[reg] = fminf(fminf(m2[reg], om2), big);
    }
  }
#pragma unroll
  for (int reg = 0; reg < 4; reg++) {
    if (l15 == quad*4 + reg) {
      int rib = wave*16 + quad*4 + reg;
      int rg = blk*64 + rib;
      float iv = 1.f / ssum[reg];
      lds_inv[rib] = iv;
      lds_idx[rib] = i1[reg];
      float md = c + m1[reg];
      mindg[rg] = md;
      atomicAdd(csum, md);
      dout[OFF_IDX + rg] = (float)i1[reg];
      if (m2[reg] - m1[reg] <= THETA) {
        int p = atomicAdd(cnt, 1);
        flag[p] = rg;
      }
    }
  }
  ASM_WAIT_LGKM();
  HARD_BARRIER();

  float ivr[4];
#pragma unroll
  for (int reg = 0; reg < 4; reg++) ivr[reg] = lds_inv[wave*16 + quad*4 + reg];

  floatx4 qacc[16];
#pragma unroll
  for (int i = 0; i < 16; i++) qacc[i] = zz;
  float* Pp = dout + OFF_P;

  // ================= PASS 2: normalized P + GEMM2 =================
  for (int kt = 0; kt < 32; kt++) {
    int cur = kt & 1;
    if (kt < 31) STAGE_E(kt+1, cur^1);
    STAGE_ET(kt);
    __builtin_amdgcn_sched_barrier(0);
    int k0 = kt*32;
    const _Float16* Ecur = &bufE[cur][0];

    floatx4 sacc[2]; sacc[0] = zz; sacc[1] = zz;
#pragma unroll
    for (int ks = 0; ks < 8; ks++) {
#pragma unroll
      for (int nt = 0; nt < 2; nt++) {
        int r = nt*16 + l15;
        half8 b = *(const half8*)(&Ecur[r*256 + (((ks*4+quad) ^ r)&31)*8]);
        sacc[nt] = __builtin_amdgcn_mfma_f32_16x16x32_f16(afrag[ks], b, sacc[nt], 0, 0, 0);
      }
    }

    // epilogue: p = exp(-10(e2-2dot)) * inv -> P (nontemporal), A-buf, col partials
#pragma unroll
    for (int nt = 0; nt < 2; nt++) {
      int kl = nt*16 + l15;
      int kcol = k0 + kl;
      float e2v = lds_e2[kcol];
      float csv = 0.f;
#pragma unroll
      for (int reg = 0; reg < 4; reg++) {
        float v = fmaf(-2.f, sacc[nt][reg], e2v);
        int rib = wave*16 + quad*4 + reg;
        float p = __expf(-10.f * v) * ivr[reg];
        __builtin_nontemporal_store(p, &Pp[(size_t)(blk*64 + rib)*1024 + kcol]);
        ldsA[rib*32 + (((kl>>3) ^ ((rib>>1)&3)))*8 + (kl&7)] = (_Float16)p;
        csv += p;
      }
      csv += __shfl_xor(csv, 16);
      csv += __shfl_xor(csv, 32);
      if (quad == 0) atomicAdd(&lds_cs[kcol], csv);
    }
    // glls (issued before the 8 P stores; in-order vmcnt => <=8 means glls done)
    ASM_WAIT_VM8_LGKM();
    HARD_BARRIER();

    // GEMM2: O(64x256) += Ptile(64x32) * Etile(32x256); wave owns 64 d-cols
    half8 bp[4];
#pragma unroll
    for (int nt = 0; nt < 4; nt++) {
      int d = wave*64 + nt*16 + l15;
      bp[nt] = *(const half8*)(&bufET[d*32 + (quad ^ ((d>>1)&3))*8]);
    }
#pragma unroll
    for (int mt = 0; mt < 4; mt++) {
      int rib = mt*16 + l15;
      half8 ap = *(const half8*)(&ldsA[rib*32 + (quad ^ ((rib>>1)&3))*8]);
#pragma unroll
      for (int nt = 0; nt < 4; nt++)
        qacc[mt*4+nt] = __builtin_amdgcn_mfma_f32_16x16x32_f16(ap, bp[nt], qacc[mt*4+nt], 0, 0, 0);
    }
    ASM_WAIT_LGKM();   // all ds_reads done before buffers are overwritten
    HARD_BARRIER();
  }

  // ---- entropy column-sum flush (one atomic per column per block) ----
#pragma unroll
  for (int j = 0; j < 4; j++)
    atomicAdd(&colg[tid + 256*j], lds_cs[tid + 256*j]);

  // ---- Q epilogue: store (already normalized), loss partial ----
  float ll = 0.f;
#pragma unroll
  for (int mt = 0; mt < 4; mt++) {
#pragma unroll
    for (int nt = 0; nt < 4; nt++) {
#pragma unroll
      for (int reg = 0; reg < 4; reg++) {
        int rib = mt*16 + quad*4 + reg;
        int dcol = wave*64 + nt*16 + l15;
        float q = qacc[mt*4+nt][reg];
        int rg = blk*64 + rib;
        __builtin_nontemporal_store(q, &dout[OFF_Q + (size_t)rg*256 + dcol]);
        float lv = latents[(size_t)rg*256 + dcol];
        float df = q - lv;
        ll = fmaf(df, df, ll);
      }
    }
  }
#pragma unroll
  for (int mbit = 1; mbit < 64; mbit <<= 1) ll += __shfl_xor(ll, mbit);
  if (lane == 0) lds_red[wave] = ll;
  __syncthreads();
  if (tid == 0) atomicAdd(lsum, lds_red[0]+lds_red[1]+lds_red[2]+lds_red[3]);

  // ---- fused HQ gather (fallback kernel re-writes flagged rows later) ----
  for (int rr = 0; rr < 16; rr++) {
    int rib = rr*4 + wave;
    int idx = lds_idx[rib];
    const float4* er = (const float4*)(emb + (size_t)idx*256);
    float4 v = er[lane];
    float* hq = dout + OFF_HQ + (size_t)(blk*64 + rib)*256 + lane*4;
    ((float2*)hq)[0] = make_float2(v.x, v.y);   // OFF_HQ is only 8B-aligned
    ((float2*)hq)[1] = make_float2(v.z, v.w);
  }
}

// exact fp32 argmin for rows whose top-2 gap was within THETA (+ HQ rewrite)
__global__ void vq_fallback(const float* __restrict__ latents, const float* __restrict__ emb,
                            char* ws, float* __restrict__ dout) {
  const float* e2g = (const float*)(ws + WS_E2);
  const int* flag = (const int*)(ws + WS_FLAG);
  const int* cnt = (const int*)(ws + WS_CNT);
  const float* mindg = (const float*)(ws + WS_MIND);
  float* csum = (float*)(ws + WS_CSUM);
  __shared__ float lrow[256];
  __shared__ float lsq[256];
  __shared__ float cshared;
  __shared__ float wv[4];
  __shared__ int wi[4];
  __shared__ int sel;
  int tid = threadIdx.x;
  int n = *cnt;
  for (int it = blockIdx.x; it < n; it += gridDim.x) {
    int rg = flag[it];
    __syncthreads();
    float v = latents[(size_t)rg*256 + tid];
    lrow[tid] = v; lsq[tid] = v*v;
    __syncthreads();
    if (tid == 0) cshared = np_pw128(lsq) + np_pw128(lsq+128);
    __syncthreads();
    float c = cshared;
    float bv = 1e30f; int bi = 0;
    for (int kk = 0; kk < 4; kk++) {
      int k = kk*256 + tid;
      const float* er = emb + (size_t)k*256;
      float dot = 0.f;
#pragma unroll 8
      for (int d = 0; d < 256; d++) dot = fmaf(lrow[d], er[d], dot);
      float dist = (c + e2g[k]) - 2.f*dot;   // reference op order
      if (dist < bv) { bv = dist; bi = k; }
    }
    int lane = tid & 63, wave = tid >> 6;
    for (int m = 1; m < 64; m <<= 1) {
      float ov = __shfl_xor(bv, m); int oi = __shfl_xor(bi, m);
      if (ov < bv || (ov == bv && oi < bi)) { bv = ov; bi = oi; }
    }
    if (lane == 0) { wv[wave] = bv; wi[wave] = bi; }
    __syncthreads();
    if (tid == 0) {
      for (int w = 1; w < 4; w++)
        if (wv[w] < bv || (wv[w] == bv && wi[w] < bi)) { bv = wv[w]; bi = wi[w]; }
      atomicAdd(csum, bv - mindg[rg]);
      dout[OFF_IDX + rg] = (float)bi;
      sel = bi;
    }
    __syncthreads();
    dout[OFF_HQ + (size_t)rg*256 + tid] = emb[(size_t)sel*256 + tid];
  }
}

__global__ void vq_finalize(char* ws, float* __restrict__ dout) {
  const float* col = (const float*)(ws + WS_COL);
  int tid = threadIdx.x;
  float a = col[tid] * (1.f/65536.f);
  float term = a * logf(a + 1e-10f);
  for (int m = 1; m < 64; m <<= 1) term += __shfl_xor(term, m);
  __shared__ float wr[16];
  int lane = tid & 63, wave = tid >> 6;
  if (lane == 0) wr[wave] = term;
  __syncthreads();
  if (tid == 0) {
    float s = 0.f;
    for (int w = 0; w < 16; w++) s += wr[w];
    dout[OFF_ENT] = -s;
    dout[OFF_LOSS] = 1.25f * (*(float*)(ws + WS_LSUM)) / (65536.f*256.f);
    dout[OFF_CM] = (*(float*)(ws + WS_CSUM)) * (1.f/65536.f);
  }
}

extern "C" void kernel_launch(void* const* d_in, const int* in_sizes, int n_in,
                              void* d_out, int out_size, void* d_ws, size_t ws_size,
                              hipStream_t stream) {
  (void)in_sizes; (void)n_in; (void)out_size; (void)ws_size;
  const float* latents = (const float*)d_in[0];
  const float* emb = (const float*)d_in[1];
  float* dout = (float*)d_out;
  char* ws = (char*)d_ws;

  vq_prep<<<1024, 256, 0, stream>>>(emb, ws);
  vq_main<<<1024, 256, 0, stream>>>(latents, emb, ws, dout);
  vq_fallback<<<1024, 256, 0, stream>>>(latents, emb, ws, dout);
  vq_finalize<<<1, 1024, 0, stream>>>(ws, dout);
}

// Round 2
// 861.438 us; speedup vs baseline: 1.3068x; 1.2963x over previous
//
#include <hip/hip_runtime.h>

typedef _Float16 half8 __attribute__((ext_vector_type(8)));
typedef float floatx4 __attribute__((ext_vector_type(4)));

#define B_TOT 65536
#define K_TOT 1024
#define D_TOT 256

// d_out offsets (float elements), concatenated reference outputs:
// quantized(B*D), vq_loss(1), entropy(1), hard_inds(B), hard_q(B*D), enc_inds(B*K), cluster(1)
#define OFF_Q    0
#define OFF_LOSS 16777216
#define OFF_ENT  16777217
#define OFF_IDX  16777218
#define OFF_HQ   16842754
#define OFF_P    33619970
#define OFF_CM   100728834

// ws offsets (bytes)
#define WS_E16   0          // K*D fp16        (512 KB)
#define WS_ETB   524288     // E^T tiled fp16: [kt][d][kl] 32x256x32 (512 KB)
#define WS_E2    1048576    // K floats
#define WS_MIND  1314816    // B floats (row min dist)
#define WS_FLAG  1576960    // B ints (flagged row list)
#define WS_CNT   1839104    // int counter
#define WS_LSUM  1839108    // float loss sum
#define WS_CSUM  1839112    // float cluster sum
#define WS_COL   1839120    // 1024 floats col sums

#define THETA 1e-4f

// async global->LDS, 16B per lane, linear LDS dest (wave-uniform base + lane*16)
__device__ __forceinline__ void gll16(const void* g, void* l) {
  __builtin_amdgcn_global_load_lds(
      (const __attribute__((address_space(1))) void*)g,
      (__attribute__((address_space(3))) void*)l, 16, 0, 0);
}

#define ASM_WAIT_LGKM()     asm volatile("s_waitcnt lgkmcnt(0)" ::: "memory")
#define ASM_WAIT_VM0_LGKM() asm volatile("s_waitcnt vmcnt(0) lgkmcnt(0)" ::: "memory")
#define ASM_WAIT_VM8_LGKM() asm volatile("s_waitcnt vmcnt(8) lgkmcnt(0)" ::: "memory")
#define HARD_BARRIER() do { __builtin_amdgcn_s_barrier(); \
  asm volatile("" ::: "memory"); __builtin_amdgcn_sched_barrier(0); } while (0)

// exact replica of numpy pairwise_sum for n=128 (<= blocksize): 8 accumulators
__device__ __forceinline__ float np_pw128(const float* a) {
  float r0=a[0],r1=a[1],r2=a[2],r3=a[3],r4=a[4],r5=a[5],r6=a[6],r7=a[7];
  for (int i = 8; i < 128; i += 8) {
    r0+=a[i+0]; r1+=a[i+1]; r2+=a[i+2]; r3+=a[i+3];
    r4+=a[i+4]; r5+=a[i+5]; r6+=a[i+6]; r7+=a[i+7];
  }
  return ((r0+r1)+(r2+r3))+((r4+r5)+(r6+r7));
}

__global__ void vq_prep(const float* __restrict__ emb, char* ws) {
  _Float16* E16 = (_Float16*)(ws + WS_E16);
  _Float16* ETb = (_Float16*)(ws + WS_ETB);
  float* e2g = (float*)(ws + WS_E2);
  int k = blockIdx.x, d = threadIdx.x;
  float v = emb[k*256 + d];
  E16[k*256 + d] = (_Float16)v;
  ETb[(k>>5)*8192 + d*32 + (k&31)] = (_Float16)v;
  __shared__ float sq[256];
  sq[d] = v*v;
  __syncthreads();
  if (d == 0) e2g[k] = np_pw128(sq) + np_pw128(sq+128);
  if (blockIdx.x == 0) {
    float* col = (float*)(ws + WS_COL);
    col[d] = 0.f; col[256+d] = 0.f; col[512+d] = 0.f; col[768+d] = 0.f;
    if (d == 0) {
      *(int*)(ws + WS_CNT) = 0;
      *(float*)(ws + WS_LSUM) = 0.f;
      *(float*)(ws + WS_CSUM) = 0.f;
    }
  }
}

// main fused kernel, two passes over K tiles.
// pass1: GEMM1 only -> row min / 2nd-min / sum(exp).  1 barrier/iter.
// pass2: GEMM1 recompute -> normalized P (regular stores) + per-wave fp16 A,
//        GEMM2 (wave owns its 16 rows x all 256 d) -> Q; entropy col partials.
//        E and E^T tiles both double-buffered -> 1 barrier/iter, counted vmcnt.
__global__ __launch_bounds__(256, 2) void vq_main(const float* __restrict__ latents,
                                                  const float* __restrict__ emb,
                                                  char* ws, float* __restrict__ dout) {
  const _Float16* E16 = (const _Float16*)(ws + WS_E16);
  const _Float16* ETb = (const _Float16*)(ws + WS_ETB);
  const float* e2g = (const float*)(ws + WS_E2);
  float* mindg = (float*)(ws + WS_MIND);
  int* flag = (int*)(ws + WS_FLAG);
  int* cnt = (int*)(ws + WS_CNT);
  float* lsum = (float*)(ws + WS_LSUM);
  float* csum = (float*)(ws + WS_CSUM);
  float* colg = (float*)(ws + WS_COL);

  // LDS total ~78.4 KB -> 2 blocks/CU
  __shared__ _Float16 bufE[2][32*256];  // [r][d], chunk' = chunk ^ r
  __shared__ _Float16 bufET[2][256*32]; // [d][kl], chunk' = chunk ^ ((d>>1)&3)
  __shared__ _Float16 ldsA[4*16*32];    // per-wave 16x32, chunk' = chunk ^ ((rl>>1)&3)
  __shared__ float lds_e2[1024];
  __shared__ float lds_cs[1024];
  __shared__ float lds_inv[64];
  __shared__ int   lds_idx[64];
  __shared__ float lds_red[4];

  int tid = threadIdx.x;
  int wave = tid >> 6, lane = tid & 63;
  int l15 = lane & 15, quad = lane >> 4;
  int blk = blockIdx.x;

  // ---- A fragments (latents rows, fp16) in registers + c = sum(l^2) ----
  half8 afrag[8];
  float c = 0.f;
  {
    int rowg = blk*64 + wave*16 + l15;
    const float* lr = latents + (size_t)rowg*256;
#pragma unroll
    for (int ks = 0; ks < 8; ks++) {
      const float4* p = (const float4*)(lr + ks*32 + quad*8);
      float4 x = p[0], y = p[1];
      half8 h;
      h[0]=(_Float16)x.x; h[1]=(_Float16)x.y; h[2]=(_Float16)x.z; h[3]=(_Float16)x.w;
      h[4]=(_Float16)y.x; h[5]=(_Float16)y.y; h[6]=(_Float16)y.z; h[7]=(_Float16)y.w;
      afrag[ks] = h;
      c += x.x*x.x + x.y*x.y + x.z*x.z + x.w*x.w
         + y.x*y.x + y.y*y.y + y.z*y.z + y.w*y.w;
    }
    c += __shfl_xor(c, 16);
    c += __shfl_xor(c, 32);
  }

  // staging: linear LDS dest, pre-swizzled global source.
  auto STAGE_E = [&](int kt, int nb) {
    int k0 = kt*32;
#pragma unroll
    for (int j = 0; j < 4; j++) {
      int r = wave*8 + j*2 + (lane>>5);
      int cch = lane & 31;
      gll16(E16 + (size_t)(k0 + r)*256 + ((cch ^ r)&31)*8,
            &bufE[nb][(wave*8 + j*2)*256]);
    }
  };
  auto STAGE_ET = [&](int kt, int nb) {
#pragma unroll
    for (int j = 0; j < 4; j++) {
      int d = wave*64 + j*16 + (lane>>2);
      int cch = lane & 3;
      gll16(ETb + (size_t)kt*8192 + d*32 + ((cch ^ ((d>>1)&3))*8),
            &bufET[nb][(wave*64 + j*16)*32]);
    }
  };

  // ---- prologue ----
#pragma unroll
  for (int j = 0; j < 4; j++) {
    lds_e2[tid + 256*j] = e2g[tid + 256*j];
    lds_cs[tid + 256*j] = 0.f;
  }
  STAGE_E(0, 0);
  ASM_WAIT_VM0_LGKM();
  HARD_BARRIER();

  float m1[4], m2[4], ssum[4]; int i1[4];
#pragma unroll
  for (int r = 0; r < 4; r++) { m1[r]=1e30f; m2[r]=1e30f; ssum[r]=0.f; i1[r]=0; }
  floatx4 zz = {0.f,0.f,0.f,0.f};

  // ================= PASS 1: sums/min only =================
  for (int kt = 0; kt < 32; kt++) {
    int cur = kt & 1;
    STAGE_E((kt+1)&31, cur^1);     // kt=31 restages tile 0 (pass-2 start)
    __builtin_amdgcn_sched_barrier(0);
    int k0 = kt*32;
    const _Float16* Ecur = &bufE[cur][0];

    floatx4 sacc[2]; sacc[0] = zz; sacc[1] = zz;
#pragma unroll
    for (int ks = 0; ks < 8; ks++) {
#pragma unroll
      for (int nt = 0; nt < 2; nt++) {
        int r = nt*16 + l15;
        half8 b = *(const half8*)(&Ecur[r*256 + (((ks*4+quad) ^ r)&31)*8]);
        sacc[nt] = __builtin_amdgcn_mfma_f32_16x16x32_f16(afrag[ks], b, sacc[nt], 0, 0, 0);
      }
    }
#pragma unroll
    for (int nt = 0; nt < 2; nt++) {
      int kl = nt*16 + l15;
      int kcol = k0 + kl;
      float e2v = lds_e2[kcol];
#pragma unroll
      for (int reg = 0; reg < 4; reg++) {
        float v = fmaf(-2.f, sacc[nt][reg], e2v);
        if (v < m1[reg]) { m2[reg] = m1[reg]; m1[reg] = v; i1[reg] = kcol; }
        else if (v < m2[reg]) m2[reg] = v;
        ssum[reg] += __expf(-10.f * v);
      }
    }
    ASM_WAIT_VM0_LGKM();
    HARD_BARRIER();
  }

  // ---- row reductions across the 16 l15 lanes ----
#pragma unroll
  for (int reg = 0; reg < 4; reg++) {
#pragma unroll
    for (int mbit = 1; mbit < 16; mbit <<= 1) {
      float om1 = __shfl_xor(m1[reg], mbit);
      int   oi1 = __shfl_xor(i1[reg], mbit);
      float om2 = __shfl_xor(m2[reg], mbit);
      float os  = __shfl_xor(ssum[reg], mbit);
      ssum[reg] += os;
      bool take = (om1 < m1[reg]) || (om1 == m1[reg] && oi1 < i1[reg]);
      float big = take ? m1[reg] : om1;
      if (take) { m1[reg] = om1; i1[reg] = oi1; }
      m2[reg] = fminf(fminf(m2[reg], om2), big);
    }
  }
#pragma unroll
  for (int reg = 0; reg < 4; reg++) {
    if (l15 == quad*4 + reg) {
      int rib = wave*16 + quad*4 + reg;
      int rg = blk*64 + rib;
      float iv = 1.f / ssum[reg];
      lds_inv[rib] = iv;
      lds_idx[rib] = i1[reg];
      float md = c + m1[reg];
      mindg[rg] = md;
      atomicAdd(csum, md);
      dout[OFF_IDX + rg] = (float)i1[reg];
      if (m2[reg] - m1[reg] <= THETA) {
        int p = atomicAdd(cnt, 1);
        flag[p] = rg;
      }
    }
  }
  STAGE_ET(0, 0);                 // E^T tile 0 for pass-2 start
  ASM_WAIT_VM0_LGKM();
  HARD_BARRIER();

  float ivr[4];
#pragma unroll
  for (int reg = 0; reg < 4; reg++) ivr[reg] = lds_inv[wave*16 + quad*4 + reg];

  floatx4 qacc[16];
#pragma unroll
  for (int i = 0; i < 16; i++) qacc[i] = zz;
  float* Pp = dout + OFF_P;

  // ================= PASS 2: normalized P + GEMM2 (1 barrier/iter) =========
  for (int kt = 0; kt < 32; kt++) {
    int cur = kt & 1;
    if (kt < 31) { STAGE_E(kt+1, cur^1); STAGE_ET(kt+1, cur^1); }
    __builtin_amdgcn_sched_barrier(0);
    int k0 = kt*32;
    const _Float16* Ecur = &bufE[cur][0];

    floatx4 sacc[2]; sacc[0] = zz; sacc[1] = zz;
#pragma unroll
    for (int ks = 0; ks < 8; ks++) {
#pragma unroll
      for (int nt = 0; nt < 2; nt++) {
        int r = nt*16 + l15;
        half8 b = *(const half8*)(&Ecur[r*256 + (((ks*4+quad) ^ r)&31)*8]);
        sacc[nt] = __builtin_amdgcn_mfma_f32_16x16x32_f16(afrag[ks], b, sacc[nt], 0, 0, 0);
      }
    }

    // epilogue: p = exp(-10(e2-2dot))*inv -> P (regular store), per-wave A, cols
#pragma unroll
    for (int nt = 0; nt < 2; nt++) {
      int kl = nt*16 + l15;
      int kcol = k0 + kl;
      float e2v = lds_e2[kcol];
      float csv = 0.f;
#pragma unroll
      for (int reg = 0; reg < 4; reg++) {
        float v = fmaf(-2.f, sacc[nt][reg], e2v);
        int rl = quad*4 + reg;
        float p = __expf(-10.f * v) * ivr[reg];
        Pp[(size_t)(blk*64 + wave*16 + rl)*1024 + kcol] = p;
        ldsA[wave*512 + rl*32 + (((kl>>3) ^ ((rl>>1)&3)))*8 + (kl&7)] = (_Float16)p;
        csv += p;
      }
      csv += __shfl_xor(csv, 16);
      csv += __shfl_xor(csv, 32);
      if (quad == 0) atomicAdd(&lds_cs[kcol], csv);
    }

    // GEMM2: wave's 16 rows x 256 d; A from own ldsA (same-wave DS order),
    // B from bufET[cur] staged LAST iteration (barrier-published).
    {
      half8 ap = *(const half8*)(&ldsA[wave*512 + l15*32 + ((quad ^ ((l15>>1)&3)))*8]);
#pragma unroll
      for (int nt = 0; nt < 16; nt++) {
        int d = nt*16 + l15;
        half8 bp = *(const half8*)(&bufET[cur][d*32 + ((quad ^ ((d>>1)&3)))*8]);
        qacc[nt] = __builtin_amdgcn_mfma_f32_16x16x32_f16(ap, bp, qacc[nt], 0, 0, 0);
      }
    }
    // 8 glls (issued first) done; only the 8 P stores may remain in flight.
    ASM_WAIT_VM8_LGKM();
    HARD_BARRIER();
  }

  // ---- entropy column-sum flush ----
#pragma unroll
  for (int j = 0; j < 4; j++)
    atomicAdd(&colg[tid + 256*j], lds_cs[tid + 256*j]);

  // ---- Q epilogue: store (already normalized), loss partial ----
  float ll = 0.f;
#pragma unroll
  for (int nt = 0; nt < 16; nt++) {
#pragma unroll
    for (int reg = 0; reg < 4; reg++) {
      int rib = wave*16 + quad*4 + reg;
      int dcol = nt*16 + l15;
      float q = qacc[nt][reg];
      int rg = blk*64 + rib;
      dout[OFF_Q + (size_t)rg*256 + dcol] = q;
      float lv = latents[(size_t)rg*256 + dcol];
      float df = q - lv;
      ll = fmaf(df, df, ll);
    }
  }
#pragma unroll
  for (int mbit = 1; mbit < 64; mbit <<= 1) ll += __shfl_xor(ll, mbit);
  if (lane == 0) lds_red[wave] = ll;
  __syncthreads();
  if (tid == 0) atomicAdd(lsum, lds_red[0]+lds_red[1]+lds_red[2]+lds_red[3]);

  // ---- fused HQ gather (fallback rewrites flagged rows later) ----
  for (int rr = 0; rr < 16; rr++) {
    int rib = rr*4 + wave;
    int idx = lds_idx[rib];
    const float4* er = (const float4*)(emb + (size_t)idx*256);
    float4 v = er[lane];
    float* hq = dout + OFF_HQ + (size_t)(blk*64 + rib)*256 + lane*4;
    ((float2*)hq)[0] = make_float2(v.x, v.y);   // OFF_HQ is only 8B-aligned
    ((float2*)hq)[1] = make_float2(v.z, v.w);
  }
}

// exact fp32 argmin for flagged rows — candidate-pruned via the stored P row.
// Candidates = {k : p_k >= pmax * e^{-10*THETA} (with margin)}; provably
// contains the exact argmin since THETA >= 2*eps(fp16 dist). Exact dot uses
// the same sequential fmaf d-order as before.
__global__ void vq_fallback(const float* __restrict__ latents, const float* __restrict__ emb,
                            char* ws, float* __restrict__ dout) {
  const float* e2g = (const float*)(ws + WS_E2);
  const int* flag = (const int*)(ws + WS_FLAG);
  const int* cnt = (const int*)(ws + WS_CNT);
  const float* mindg = (const float*)(ws + WS_MIND);
  float* csum = (float*)(ws + WS_CSUM);
  const float* P = dout + OFF_P;
  __shared__ float lrow[256];
  __shared__ float lsq[256];
  __shared__ float cshared;
  __shared__ float pmax_s;
  __shared__ float redp[4];
  __shared__ float wv[4];
  __shared__ int wi[4];
  __shared__ int sel;
  int tid = threadIdx.x;
  int lane = tid & 63, wave = tid >> 6;
  int n = *cnt;
  for (int it = blockIdx.x; it < n; it += gridDim.x) {
    int rg = flag[it];
    __syncthreads();
    float v = latents[(size_t)rg*256 + tid];
    lrow[tid] = v; lsq[tid] = v*v;
    // load this row's P values (4 per thread; OFF_P only 8B-aligned -> float2)
    const float2* pr = (const float2*)(P + (size_t)rg*1024 + tid*4);
    float2 pa = pr[0], pb = pr[1];
    float pm = fmaxf(fmaxf(pa.x, pa.y), fmaxf(pb.x, pb.y));
    for (int m = 1; m < 64; m <<= 1) pm = fmaxf(pm, __shfl_xor(pm, m));
    if (lane == 0) redp[wave] = pm;
    __syncthreads();
    if (tid == 0) {
      pmax_s = fmaxf(fmaxf(redp[0], redp[1]), fmaxf(redp[2], redp[3]));
      cshared = np_pw128(lsq) + np_pw128(lsq+128);
    }
    __syncthreads();
    float thr = pmax_s * 0.9980f;   // e^{-10*THETA}=0.9990, with safety margin
    float c = cshared;
    float bv = 1e30f; int bi = 0x40000000;
    float pv[4] = {pa.x, pa.y, pb.x, pb.y};
#pragma unroll
    for (int j = 0; j < 4; j++) {
      if (pv[j] >= thr) {
        int k = tid*4 + j;
        const float* er = emb + (size_t)k*256;
        float dot = 0.f;
#pragma unroll 8
        for (int d = 0; d < 256; d++) dot = fmaf(lrow[d], er[d], dot);
        float dist = (c + e2g[k]) - 2.f*dot;   // reference op order
        if (dist < bv) { bv = dist; bi = k; }  // within-thread k ascending
      }
    }
    for (int m = 1; m < 64; m <<= 1) {
      float ov = __shfl_xor(bv, m); int oi = __shfl_xor(bi, m);
      if (ov < bv || (ov == bv && oi < bi)) { bv = ov; bi = oi; }
    }
    if (lane == 0) { wv[wave] = bv; wi[wave] = bi; }
    __syncthreads();
    if (tid == 0) {
      for (int w = 1; w < 4; w++)
        if (wv[w] < bv || (wv[w] == bv && wi[w] < bi)) { bv = wv[w]; bi = wi[w]; }
      atomicAdd(csum, bv - mindg[rg]);
      dout[OFF_IDX + rg] = (float)bi;
      sel = bi;
    }
    __syncthreads();
    dout[OFF_HQ + (size_t)rg*256 + tid] = emb[(size_t)sel*256 + tid];
  }
}

__global__ void vq_finalize(char* ws, float* __restrict__ dout) {
  const float* col = (const float*)(ws + WS_COL);
  int tid = threadIdx.x;
  float a = col[tid] * (1.f/65536.f);
  float term = a * logf(a + 1e-10f);
  for (int m = 1; m < 64; m <<= 1) term += __shfl_xor(term, m);
  __shared__ float wr[16];
  int lane = tid & 63, wave = tid >> 6;
  if (lane == 0) wr[wave] = term;
  __syncthreads();
  if (tid == 0) {
    float s = 0.f;
    for (int w = 0; w < 16; w++) s += wr[w];
    dout[OFF_ENT] = -s;
    dout[OFF_LOSS] = 1.25f * (*(float*)(ws + WS_LSUM)) / (65536.f*256.f);
    dout[OFF_CM] = (*(float*)(ws + WS_CSUM)) * (1.f/65536.f);
  }
}

extern "C" void kernel_launch(void* const* d_in, const int* in_sizes, int n_in,
                              void* d_out, int out_size, void* d_ws, size_t ws_size,
                              hipStream_t stream) {
  (void)in_sizes; (void)n_in; (void)out_size; (void)ws_size;
  const float* latents = (const float*)d_in[0];
  const float* emb = (const float*)d_in[1];
  float* dout = (float*)d_out;
  char* ws = (char*)d_ws;

  vq_prep<<<1024, 256, 0, stream>>>(emb, ws);
  vq_main<<<1024, 256, 0, stream>>>(latents, emb, ws, dout);
  vq_fallback<<<1024, 256, 0, stream>>>(latents, emb, ws, dout);
  vq_finalize<<<1, 1024, 0, stream>>>(ws, dout);
}